// Round 1
// baseline (27.084 us; speedup 1.0000x reference)
//
#include <hip/hip_runtime.h>
#include <cmath>

// SpikesToTimesDecoder: input [T, B, N] fp32 0/1 raster -> output [3, B, N]
// fp32 times (t * 0.001) of the first 3 spikes per channel, inf-padded.
//
// One thread per (b, n) channel. Lane i of a wave handles channel c = base+i,
// so each timestep's loads across a wave are 64 consecutive floats = 256 B
// fully-coalesced. Chunked by 16 timesteps for memory-level parallelism;
// per-wave early exit once all 64 lanes have found 3 spikes (expected exit
// t ~ 200 << 512 at 5% spike rate) -> skips fetching most of the input.

constexpr int K_SPIKES = 3;
constexpr int CHUNK = 16;

__global__ __launch_bounds__(256) void spikes_to_times_kernel(
    const float* __restrict__ in, float* __restrict__ out,
    int BN, int T, float dt) {
  const int c = blockIdx.x * blockDim.x + threadIdx.x;
  if (c >= BN) return;

  float t0 = INFINITY, t1 = INFINITY, t2 = INFINITY;
  int cnt = 0;
  const float* p = in + c;

  for (int t = 0; t < T; t += CHUNK) {
    float v[CHUNK];
#pragma unroll
    for (int j = 0; j < CHUNK; ++j) {
      v[j] = p[(size_t)(t + j) * (size_t)BN];
    }
#pragma unroll
    for (int j = 0; j < CHUNK; ++j) {
      const bool s = v[j] > 0.0f;
      const float tt = (float)(t + j);
      if (s && cnt == 0) t0 = tt;
      if (s && cnt == 1) t1 = tt;
      if (s && cnt == 2) t2 = tt;
      cnt += s ? 1 : 0;
    }
    // Whole wave done? (all 64 lanes found K_SPIKES spikes)
    if (__all(cnt >= K_SPIKES)) break;
  }

  out[c]          = t0 * dt;
  out[BN + c]     = t1 * dt;
  out[2 * BN + c] = t2 * dt;
}

extern "C" void kernel_launch(void* const* d_in, const int* in_sizes, int n_in,
                              void* d_out, int out_size, void* d_ws, size_t ws_size,
                              hipStream_t stream) {
  const float* in = (const float*)d_in[0];
  float* out = (float*)d_out;

  const int BN = out_size / K_SPIKES;      // B * N channels
  const int T = in_sizes[0] / BN;          // timesteps

  const int block = 256;
  const int grid = (BN + block - 1) / block;
  hipLaunchKernelGGL(spikes_to_times_kernel, dim3(grid), dim3(block), 0, stream,
                     in, out, BN, T, 0.001f);
}